// Round 4
// baseline (534.046 us; speedup 1.0000x reference)
//
#include <hip/hip_runtime.h>
#include <math.h>

// PixPro fused masked all-pairs cosine loss, MI355X (gfx950).
// B=2048, C=256, H=W=7 -> P=49 pixels.
// out[b] = -(1/2401) * sum_{p,q} wt[p][q] * dot(base_p, mom_q)/max(nb_p*nm_q, eps)
// wt[p][q] = [base_A[p,q]==1] + [moment_A[q,p]==1].
//
// v6 structure (from r3 post-mortem: latency-bound, occupancy stuck ~19%):
//  - 1 batch per 128-thread block (2 waves, channel split 128+128), 2048 blocks.
//    LDS cut 23 KB -> ~9 KB (tests the hypothesis that schedulable LDS ~64 KB
//    caps blocks/CU at 2 = 8 waves/CU = the measured 19%).
//  - NO explicit waitcnt in the slab loop. Rotating 4-deep pipeline:
//    step s: [write other buf <- reg set (slab s+1)] [global-load that set
//    (slab s+5)] [compute current buf]. RAW covered by a full FMA phase;
//    WAR safe via per-wave in-order DS; compiler emits counted waits.
//    Global prefetch in flight ~4 compute phases (~1600 cyc > 900 HBM).
//  - staging spread over all 64 lanes: lane<49 base pixel lane; lanes 49-63
//    mom pixels 0-14; item1 (lanes<34) mom pixels 15-48. Each lane stages the
//    same pixel it norm-accumulates. One ds_write_b128 per item (bank-spread).
//  - dense [p][4ch] layout (conflict-free b128 frags, proven in r3: 11.5M->200K).
//  - half-combine exchange reuses slab space in 2 chunked passes (no extra LDS).

constexpr int NB     = 2048;
constexpr int NC     = 256;
constexpr int NP     = 49;            // 7*7 pixels
constexpr int SLAB_C = 4;             // channels per slab
constexpr int FW     = NP * SLAB_C;   // 196 words per feature per slab
constexpr int BUFW   = 2 * FW;        // 392 words per slab buffer (base|mom)
constexpr int WREG   = 2 * BUFW;      // 784 words per wave region (2 buffers)
constexpr int NSLABW = (NC / 2) / SLAB_C;  // 32 slabs per wave
constexpr float EPS  = 1e-6f;

__global__ __launch_bounds__(128, 2)
void pixpro_kernel(const float* __restrict__ gbase,
                   const float* __restrict__ gmom,
                   const int*   __restrict__ A1,
                   const int*   __restrict__ A2,
                   float*       __restrict__ out)
{
    __shared__ unsigned char wtb[NP * NP];          // combined weights, u8 {0,1,2}
    __shared__ __align__(16) float slab[2][WREG];   // per-wave double buffer / exchange

    const int tid  = threadIdx.x;
    const int wave = tid >> 6;        // 0..1
    const int lane = tid & 63;
    const int b    = blockIdx.x;      // one batch per block
    const int half = wave;            // channel half [0,128) / [128,256)

    // --- stage combined mask weights as u8 (block-shared) ---
    for (int t = tid; t < NP * NP; t += 128) {
        int p = t / NP, q = t - p * NP;
        wtb[t] = (unsigned char)((A1[t] == 1 ? 1 : 0) + (A2[q * NP + p] == 1 ? 1 : 0));
    }
    __syncthreads();

    float* const sl = slab[wave];

    const int lp = lane & 7, lq = lane >> 3;
    const int p0 = (lp < 7 ? lp : 6) * 7;   // lp==7 / lq==7 lanes duplicate tile 6, masked later
    const int q0 = (lq < 7 ? lq : 6) * 7;

    const float* gb = gbase + (size_t)b * (NC * NP) + (size_t)half * (128 * NP);
    const float* gm = gmom  + (size_t)b * (NC * NP) + (size_t)half * (128 * NP);

    // staging/norm assignment:
    //   item0: lane<49 -> base pixel lane ; lane>=49 -> mom pixel lane-49
    //   item1: lane<34 -> mom pixel 15+lane (else absent)
    const bool  is_b = (lane < NP);
    const bool  has1 = (lane < 34);
    const float* gi0 = is_b ? (gb + lane) : (gm + (lane - NP));
    const float* gi1 = gm + 15 + (has1 ? lane : 0);

    const int w0 = is_b ? (4 * lane) : (FW + 4 * (lane - NP));   // item0 LDS word off
    const int w1 = FW + 4 * (has1 ? (15 + lane) : 48);           // item1 LDS word off

#define LOADSET(R0, R1, s) do {                                            \
        const float* _p0 = gi0 + (s) * (SLAB_C * NP);                      \
        R0.x = _p0[0]; R0.y = _p0[NP]; R0.z = _p0[2*NP]; R0.w = _p0[3*NP]; \
        if (has1) {                                                        \
            const float* _p1 = gi1 + (s) * (SLAB_C * NP);                  \
            R1.x = _p1[0]; R1.y = _p1[NP]; R1.z = _p1[2*NP]; R1.w = _p1[3*NP]; \
        }                                                                  \
    } while (0)

#define WRITESET(R0, R1, boff) do {                                        \
        *(float4*)(sl + (boff) + w0) = R0;                                 \
        if (has1) *(float4*)(sl + (boff) + w1) = R1;                       \
    } while (0)

    float acc[7][7];
    #pragma unroll
    for (int j = 0; j < 7; ++j)
        #pragma unroll
        for (int i = 0; i < 7; ++i) acc[j][i] = 0.0f;
    float nrm0 = 0.0f, nrm1 = 0.0f;

    auto compute = [&](const int Boff) {
        const float* base_ = sl + Boff;
        float4 a4 = *(const float4*)(base_ + w0);
        float4 b4 = *(const float4*)(base_ + w1);
        nrm0 = fmaf(a4.x, a4.x, fmaf(a4.y, a4.y, fmaf(a4.z, a4.z, fmaf(a4.w, a4.w, nrm0))));
        nrm1 = fmaf(b4.x, b4.x, fmaf(b4.y, b4.y, fmaf(b4.z, b4.z, fmaf(b4.w, b4.w, nrm1))));
        float4 mv[7];
        #pragma unroll
        for (int j = 0; j < 7; ++j)
            mv[j] = *(const float4*)(base_ + FW + 4 * (q0 + j));
        #pragma unroll
        for (int i = 0; i < 7; ++i) {
            float4 bv = *(const float4*)(base_ + 4 * (p0 + i));
            #pragma unroll
            for (int j = 0; j < 7; ++j) {
                float t0 = fmaf(bv.x, mv[j].x, acc[j][i]);
                t0       = fmaf(bv.y, mv[j].y, t0);
                t0       = fmaf(bv.z, mv[j].z, t0);
                acc[j][i] = fmaf(bv.w, mv[j].w, t0);
            }
        }
    };

    // --- 4-deep rotating pipeline: sets a,b,c,d hold slabs s..s+3 ---
    float4 a0f = {}, a1f = {}, b0f = {}, b1f = {};
    float4 c0f = {}, c1f = {}, d0f = {}, d1f = {};
    LOADSET(a0f, a1f, 0);
    LOADSET(b0f, b1f, 1);
    LOADSET(c0f, c1f, 2);
    LOADSET(d0f, d1f, 3);
    WRITESET(a0f, a1f, 0);        // buf0 <- slab 0
    LOADSET(a0f, a1f, 4);         // set a rotates to slab 4

    for (int s4 = 0; s4 < NSLABW; s4 += 4) {
        // step 0: compute slab s4 (buf0); buf1 <- slab s4+1 (set b); b <- slab s4+5
        if (s4 + 1 < NSLABW) WRITESET(b0f, b1f, BUFW);
        if (s4 + 5 < NSLABW) LOADSET(b0f, b1f, s4 + 5);
        compute(0);
        // step 1: compute slab s4+1 (buf1); buf0 <- slab s4+2 (set c); c <- slab s4+6
        if (s4 + 2 < NSLABW) WRITESET(c0f, c1f, 0);
        if (s4 + 6 < NSLABW) LOADSET(c0f, c1f, s4 + 6);
        compute(BUFW);
        // step 2: compute slab s4+2 (buf0); buf1 <- slab s4+3 (set d); d <- slab s4+7
        if (s4 + 3 < NSLABW) WRITESET(d0f, d1f, BUFW);
        if (s4 + 7 < NSLABW) LOADSET(d0f, d1f, s4 + 7);
        compute(0);
        // step 3: compute slab s4+3 (buf1); buf0 <- slab s4+4 (set a); a <- slab s4+8
        if (s4 + 4 < NSLABW) WRITESET(a0f, a1f, 0);
        if (s4 + 8 < NSLABW) LOADSET(a0f, a1f, s4 + 8);
        compute(BUFW);
    }

#undef LOADSET
#undef WRITESET

    // --- combine the two channel-halves (chunked through the freed slab space) ---
    __syncthreads();                      // all slab reads done; reuse as exchange
    float* const ex   = &slab[0][0];      // 2*WREG = 1568 words available
    const bool active = (lp < 7) && (lq < 7);
    const int  tix    = lq * 7 + lp;      // 0..48 for active lanes

    // pass 0: norms + acc rows j=0..3  (128 + 49*28 = 1500 words <= 1568)
    if (half) {
        ex[lane]      = nrm0;
        ex[64 + lane] = nrm1;
        if (active) {
            #pragma unroll
            for (int j = 0; j < 4; ++j)
                #pragma unroll
                for (int i = 0; i < 7; ++i)
                    ex[128 + tix * 28 + j * 7 + i] = acc[j][i];
        }
    }
    __syncthreads();
    if (!half) {
        nrm0 += ex[lane];
        nrm1 += ex[64 + lane];
        if (active) {
            #pragma unroll
            for (int j = 0; j < 4; ++j)
                #pragma unroll
                for (int i = 0; i < 7; ++i)
                    acc[j][i] += ex[128 + tix * 28 + j * 7 + i];
        }
    }
    __syncthreads();
    // pass 1: acc rows j=4..6  (49*21 = 1029 words)
    if (half && active) {
        #pragma unroll
        for (int j = 4; j < 7; ++j)
            #pragma unroll
            for (int i = 0; i < 7; ++i)
                ex[tix * 21 + (j - 4) * 7 + i] = acc[j][i];
    }
    __syncthreads();

    if (!half) {  // even wave finishes
        if (active) {
            #pragma unroll
            for (int j = 4; j < 7; ++j)
                #pragma unroll
                for (int i = 0; i < 7; ++i)
                    acc[j][i] += ex[tix * 21 + (j - 4) * 7 + i];
        }
        // redistribute combined squared norms within the wave:
        // ex[0..48] = base pixel sums; ex[49..97] = mom pixel sums
        // (reads above issued before these writes; per-wave DS is in-order)
        ex[lane] = nrm0;                       // lanes 0..48 base, 49..63 mom[0..14]
        if (lane < 34) ex[64 + lane] = nrm1;   // mom[15..48]
        asm volatile("s_waitcnt lgkmcnt(0)" ::: "memory");

        float nbv[7], nmv[7];
        #pragma unroll
        for (int i = 0; i < 7; ++i) nbv[i] = sqrtf(ex[p0 + i]);
        #pragma unroll
        for (int j = 0; j < 7; ++j) nmv[j] = sqrtf(ex[NP + q0 + j]);

        float sum = 0.0f;
        if (active) {
            #pragma unroll
            for (int j = 0; j < 7; ++j)
                #pragma unroll
                for (int i = 0; i < 7; ++i) {
                    float w     = (float)wtb[(p0 + i) * NP + (q0 + j)];
                    float denom = fmaxf(nbv[i] * nmv[j], EPS);
                    sum += w * acc[j][i] / denom;
                }
        }
        #pragma unroll
        for (int m = 32; m; m >>= 1) sum += __shfl_xor(sum, m, 64);
        if (lane == 0) out[b] = sum * (-1.0f / 2401.0f);
    }
}

extern "C" void kernel_launch(void* const* d_in, const int* in_sizes, int n_in,
                              void* d_out, int out_size, void* d_ws, size_t ws_size,
                              hipStream_t stream)
{
    (void)in_sizes; (void)n_in; (void)d_ws; (void)ws_size; (void)out_size;
    const float* base = (const float*)d_in[0];
    const float* mom  = (const float*)d_in[1];
    const int*   A1   = (const int*)d_in[2];
    const int*   A2   = (const int*)d_in[3];
    float*       out  = (float*)d_out;

    pixpro_kernel<<<NB, 128, 0, stream>>>(base, mom, A1, A2, out);
}

// Round 5
// 229.177 us; speedup vs baseline: 2.3303x; 2.3303x over previous
//
#include <hip/hip_runtime.h>
#include <math.h>

// PixPro fused masked all-pairs cosine loss, MI355X (gfx950).
// B=2048, C=256, H=W=7 -> P=49 pixels.
// out[b] = -(1/2401) * sum_{p,q} wt[p][q] * dot(base_p, mom_q)/max(nb_p*nm_q, eps)
// wt[p][q] = [base_A[p,q]==1] + [moment_A[q,p]==1].
//
// v7: MFMA (split-bf16) rewrite.
//  - Per batch: D = base^T . mom  (49x49, K=256) on matrix cores.
//    fp32 x = hi + lo: hi = x & 0xFFFF0000 (exact), lo = bf16(x - hi).
//    D ~= Ahi.Bhi + Ahi.Blo + Alo.Bhi  (3 mfma per tile-kstep; lo.lo dropped,
//    ~1.5e-5 relative on dots -> ~1e-6 absolute on the averaged output).
//  - One 256-thread block (4 waves) per batch, grid 2048.
//    Wave w owns m-tile w (rows 16w..16w+15); 4 n-tiles each; acc = 4x f32x4.
//  - K-panels of 32 channels, double-buffered LDS. Four pixel-major bf16
//    matrices per buffer [pixel][32ch]: Ahi, Alo, Bhi, Blo. Row pitch 40
//    shorts (80 B) -> frag ds_read_b128 is 2-way bank aliased (free, m136).
//    Rows 49..63 of each tile read into the next matrix region (garbage) --
//    affects only discarded D rows/cols; 15-row tail pad keeps it in-bounds.
//  - Staging: lane l<49 <-> pixel l; wave w loads channels 8w..8w+7 of the
//    panel (8 scalar stride-49 loads per feature = coalesced 196B segments),
//    converts hi/lo in-register, writes one b128 per matrix row-slice.
//    Norms accumulate in fp32 from the original values during conversion.
//  - T14 ordering: loads issue at loop top, mfma compute runs, cvt+ds_write
//    after (HBM latency hides under the mfma phase). One barrier per k-step.

constexpr int NB  = 2048;
constexpr int NC  = 256;
constexpr int NP  = 49;
constexpr float EPS = 1e-6f;

constexpr int PW      = 40;                  // shorts per LDS matrix row (80 B)
constexpr int MROW    = 49;                  // real rows per matrix
constexpr int BUFROWS = 4 * MROW;            // 196 rows per k-panel buffer
constexpr int TOTROWS = 2 * BUFROWS + 15;    // + tail pad for tile-3 overflow reads

typedef short bf16x8 __attribute__((ext_vector_type(8)));   // 8 bf16 = 4 VGPR
typedef float f32x4  __attribute__((ext_vector_type(4)));   // mfma accumulator

__global__ __launch_bounds__(256, 2)
void pixpro_kernel(const float* __restrict__ gbase,
                   const float* __restrict__ gmom,
                   const int*   __restrict__ A1,
                   const int*   __restrict__ A2,
                   float*       __restrict__ out)
{
    __shared__ unsigned char wtb[NP * NP];                    // weights u8 {0,1,2}
    __shared__ __align__(16) unsigned short mats[TOTROWS * PW];
    __shared__ float nbp[4][NP], nmp[4][NP];                  // per-wave norm partials
    __shared__ float sbc[NP], smc[NP];                        // combined sq-norms
    __shared__ float redsum[4];

    const int tid  = threadIdx.x;
    const int wave = tid >> 6;
    const int lane = tid & 63;
    const int b    = blockIdx.x;

    // --- stage combined mask weights ---
    for (int t = tid; t < NP * NP; t += 256) {
        int p = t / NP, q = t - p * NP;
        wtb[t] = (unsigned char)((A1[t] == 1 ? 1 : 0) + (A2[q * NP + p] == 1 ? 1 : 0));
    }

    const float* gB = gbase + (size_t)b * (NC * NP);
    const float* gM = gmom  + (size_t)b * (NC * NP);
    const bool   ld = (lane < NP);

    float nrmb = 0.f, nrmm = 0.f;

    // issue the 16 scalar gathers for a panel (wave w: channels 32*panel+8w..+7)
    auto LOADS = [&](int panel, float (&x)[2][8]) {
        if (!ld) return;
        const float* pB = gB + (32 * panel + 8 * wave) * NP + lane;
        const float* pM = gM + (32 * panel + 8 * wave) * NP + lane;
        #pragma unroll
        for (int j = 0; j < 8; ++j) x[0][j] = pB[j * NP];
        #pragma unroll
        for (int j = 0; j < 8; ++j) x[1][j] = pM[j * NP];
    };

    // split hi/lo, accumulate norms, write one b128 per matrix
    auto CVTWRITE = [&](int buf, float (&x)[2][8]) {
        if (!ld) return;
        #pragma unroll
        for (int f = 0; f < 2; ++f) {
            unsigned int hi[4], lo[4];
            float n = 0.f;
            #pragma unroll
            for (int jp = 0; jp < 4; ++jp) {
                float x0 = x[f][2 * jp], x1 = x[f][2 * jp + 1];
                unsigned int u0 = __float_as_uint(x0) & 0xFFFF0000u;
                unsigned int u1 = __float_as_uint(x1) & 0xFFFF0000u;
                hi[jp] = u1 | (u0 >> 16);                 // packed bf16 pair (hi)
                float l0 = x0 - __uint_as_float(u0);      // exact residual
                float l1 = x1 - __uint_as_float(u1);
                unsigned int r;
                asm("v_cvt_pk_bf16_f32 %0, %1, %2" : "=v"(r) : "v"(l0), "v"(l1));
                lo[jp] = r;                               // packed bf16 pair (lo)
                n = fmaf(x0, x0, fmaf(x1, x1, n));        // fp32 norm (exact data)
            }
            if (f == 0) nrmb += n; else nrmm += n;
            unsigned short* mh = mats + ((size_t)buf * BUFROWS + (2 * f + 0) * MROW + lane) * PW + 8 * wave;
            unsigned short* ml = mats + ((size_t)buf * BUFROWS + (2 * f + 1) * MROW + lane) * PW + 8 * wave;
            *reinterpret_cast<uint4*>(mh) = make_uint4(hi[0], hi[1], hi[2], hi[3]);
            *reinterpret_cast<uint4*>(ml) = make_uint4(lo[0], lo[1], lo[2], lo[3]);
        }
    };

    f32x4 acc[4];
    const f32x4 zz = {0.f, 0.f, 0.f, 0.f};
    acc[0] = zz; acc[1] = zz; acc[2] = zz; acc[3] = zz;

    const int fr = lane & 15;     // frag row/col within tile
    const int kc = lane >> 4;     // k-chunk (8 bf16 each)

    auto COMPUTE = [&](int buf) {
        const unsigned short* mb = mats + (size_t)buf * BUFROWS * PW;
        // A-frag: A[m = 16w+fr][k = 8*kc .. +7]  (pixel-major row read)
        const unsigned short* pA = mb + (16 * wave + fr) * PW + kc * 8;
        bf16x8 Ah = *(const bf16x8*)(pA);
        bf16x8 Al = *(const bf16x8*)(pA + MROW * PW);
        #pragma unroll
        for (int t = 0; t < 4; ++t) {
            // B-frag: B[k = 8*kc..+7][n = 16t+fr] = momT[16t+fr][k]
            const unsigned short* pBm = mb + (2 * MROW + 16 * t + fr) * PW + kc * 8;
            bf16x8 Bh = *(const bf16x8*)(pBm);
            bf16x8 Bl = *(const bf16x8*)(pBm + MROW * PW);
            acc[t] = __builtin_amdgcn_mfma_f32_16x16x32_bf16(Ah, Bh, acc[t], 0, 0, 0);
            acc[t] = __builtin_amdgcn_mfma_f32_16x16x32_bf16(Ah, Bl, acc[t], 0, 0, 0);
            acc[t] = __builtin_amdgcn_mfma_f32_16x16x32_bf16(Al, Bh, acc[t], 0, 0, 0);
        }
    };

    // --- prologue: stage panel 0 into buf 0 ---
    {
        float x0[2][8];
        LOADS(0, x0);
        CVTWRITE(0, x0);
    }
    __syncthreads();

    // --- main loop: 8 k-panels, double-buffered, one barrier each ---
    #pragma unroll 2
    for (int k = 0; k < 8; ++k) {
        float xn[2][8];
        if (k + 1 < 8) LOADS(k + 1, xn);      // issue early (hide under mfma)
        COMPUTE(k & 1);
        if (k + 1 < 8) CVTWRITE((k & 1) ^ 1, xn);
        __syncthreads();
    }

    // --- combine norms ---
    if (ld) { nbp[wave][lane] = nrmb; nmp[wave][lane] = nrmm; }
    __syncthreads();
    if (wave == 0 && ld) {
        sbc[lane] = nbp[0][lane] + nbp[1][lane] + nbp[2][lane] + nbp[3][lane];
        smc[lane] = nmp[0][lane] + nmp[1][lane] + nmp[2][lane] + nmp[3][lane];
    }
    __syncthreads();

    // --- epilogue: lane holds D[16w + 4*kc + r][16t + fr] in acc[t][r] ---
    float nbr[4];
    #pragma unroll
    for (int r = 0; r < 4; ++r) {
        int row = 16 * wave + 4 * kc + r;
        nbr[r] = (row < NP) ? sqrtf(sbc[row]) : 0.f;
    }
    float sum = 0.f;
    #pragma unroll
    for (int t = 0; t < 4; ++t) {
        int col = 16 * t + fr;
        if (col < NP) {
            float nmc = sqrtf(smc[col]);
            #pragma unroll
            for (int r = 0; r < 4; ++r) {
                int row = 16 * wave + 4 * kc + r;
                if (row < NP) {
                    float w     = (float)wtb[row * NP + col];
                    float denom = fmaxf(nbr[r] * nmc, EPS);
                    sum += w * acc[t][r] / denom;
                }
            }
        }
    }
    #pragma unroll
    for (int m = 32; m; m >>= 1) sum += __shfl_xor(sum, m, 64);
    if (lane == 0) redsum[wave] = sum;
    __syncthreads();
    if (tid == 0)
        out[b] = -(redsum[0] + redsum[1] + redsum[2] + redsum[3]) * (1.0f / 2401.0f);
}

extern "C" void kernel_launch(void* const* d_in, const int* in_sizes, int n_in,
                              void* d_out, int out_size, void* d_ws, size_t ws_size,
                              hipStream_t stream)
{
    (void)in_sizes; (void)n_in; (void)d_ws; (void)ws_size; (void)out_size;
    const float* base = (const float*)d_in[0];
    const float* mom  = (const float*)d_in[1];
    const int*   A1   = (const int*)d_in[2];
    const int*   A2   = (const int*)d_in[3];
    float*       out  = (float*)d_out;

    pixpro_kernel<<<NB, 256, 0, stream>>>(base, mom, A1, A2, out);
}